// Round 4
// baseline (121.920 us; speedup 1.0000x reference)
//
#include <hip/hip_runtime.h>

// SIR recurrence: 2047 strictly-sequential steps of a 4-state quadratic map.
// R3 (resubmitted unchanged — R3 bench was a GPU-acquisition timeout, no data).
// R2 post-mortem showed the b128 store forced a VGPR-quad reuse ->
// per-step lgkmcnt wait (~30cyc exposed). Fix: SoA LDS arrays, each value
// stored from its live register (compiler pairs into ds_write2_b32, imm
// offsets). Serial body ~6 VALU + ~2 DS per step, dep chain = 3.
//
// FP op order FROZEN (absmax == 0.0 in R1 and R2):
//   t  = u*v
//   c  = fmaf(gamma, t, delta)     gamma = w3*w3/1000, delta = fmaf(w3,b3,b3)
//   nu = fmaf(L, u, c)             L = 1 - w2sq - w4sq
//   nv = v - c
//   s1 = fmaf(w2sq, u, s1)
//   s3 = fmaf(w4sq, u, s3)

__global__ __launch_bounds__(256) void sir_kernel(
    const float* __restrict__ x, const float* __restrict__ w2p,
    const float* __restrict__ w3p, const float* __restrict__ b3p,
    const float* __restrict__ w4p, const int* __restrict__ np,
    float* __restrict__ out) {
  __shared__ float bu[2048];   // nu_i  -> out col 0
  __shared__ float bv[2048];   // nv_i  -> out col 2
  __shared__ float bs1[2048];  // s1_i  -> out col 1
  __shared__ float bs3[2048];  // s3_i  -> out col 3
  const int n = *np;
  const int rows = n - 1;  // 2047
  const int tid = threadIdx.x;

  if (tid == 0) {
    const float w2 = *w2p, w3 = *w3p, b3 = *b3p, w4 = *w4p;
    const float w2sq  = w2 * w2;
    const float w4sq  = w4 * w4;
    const float L     = 1.0f - w2sq - w4sq;
    const float gamma = (w3 * w3) / 1000.0f;
    const float delta = fmaf(w3, b3, b3);

    float u  = x[0];
    float s1 = x[1];
    float v  = x[2];
    float s3 = x[3];

#pragma unroll 32
    for (int i = 0; i < rows; ++i) {
      const float t  = u * v;
      const float c  = fmaf(gamma, t, delta);
      const float nu = fmaf(L, u, c);
      const float nv = v - c;
      s1 = fmaf(w2sq, u, s1);
      s3 = fmaf(w4sq, u, s3);
      u = nu;
      v = nv;
      // SoA stores from live regs: no quad assembly, no single-reg-set reuse.
      bu[i]  = nu;
      bv[i]  = nv;
      bs1[i] = s1;
      bs3[i] = s3;
    }
  }
  __syncthreads();  // other 255 threads sleep here

  // Parallel writeback: 5-wide rows + col-4 zeros (d_out re-poisoned 0xAA).
  for (int r = tid; r < rows; r += 256) {
    float* __restrict__ o = out + 5 * r;
    o[0] = bu[r];
    o[1] = bs1[r];
    o[2] = bv[r];
    o[3] = bs3[r];
    o[4] = 0.0f;
  }
}

extern "C" void kernel_launch(void* const* d_in, const int* in_sizes, int n_in,
                              void* d_out, int out_size, void* d_ws, size_t ws_size,
                              hipStream_t stream) {
  const float* x   = (const float*)d_in[0];
  const float* w2  = (const float*)d_in[1];
  const float* w3  = (const float*)d_in[2];
  const float* b3  = (const float*)d_in[3];
  const float* w4  = (const float*)d_in[4];
  const int*   n   = (const int*)d_in[5];
  float* out = (float*)d_out;
  sir_kernel<<<1, 256, 0, stream>>>(x, w2, w3, b3, w4, n, out);
}